// Round 8
// baseline (422.397 us; speedup 1.0000x reference)
//
#include <hip/hip_runtime.h>
#include <hip/hip_bf16.h>

#define N1 8192
#define N2 8192
#define CDIM 128
#define HC 60
#define WC 80
#define HIMG 480
#define WIMG 640
#define INV_DENOM (1.0f / (8192.0f * 256.0f))

using bf16x8 = __attribute__((ext_vector_type(8))) short;
using f32x4  = __attribute__((ext_vector_type(4))) float;

__device__ __forceinline__ ushort f2bf(float f) {
    union { float f; unsigned u; } x; x.f = f;
    unsigned u = x.u;
    unsigned r = (u + 0x7FFFu + ((u >> 16) & 1u)) >> 16;
    return (ushort)r;
}
__device__ __forceinline__ float bf2f(unsigned bits) {
    union { unsigned u; float f; } x; x.u = bits << 16; return x.f;
}
__device__ __forceinline__ unsigned key2bits(unsigned k) {
    return k ^ ((k & 0x8000u) ? 0x8000u : 0xFFFFu);
}
// packed pair of bf16 bits -> packed pair of monotone u16 keys
__device__ __forceinline__ unsigned pair2key(unsigned x) {
    return x ^ 0x80008000u ^ (((x >> 15) & 0x00010001u) * 0x7FFFu);
}

// ---------- fp32 -> bf16 convert (vectorized) ----------
__global__ void cvt_kernel(const float* __restrict__ in, ushort* __restrict__ out, int n4) {
    int i = blockIdx.x * blockDim.x + threadIdx.x;
    if (i < n4) {
        float4 v = ((const float4*)in)[i];
        ushort4 o;
        o.x = f2bf(v.x); o.y = f2bf(v.y); o.z = f2bf(v.z); o.w = f2bf(v.w);
        ((ushort4*)out)[i] = o;
    }
}

// ---------- positive term ----------
__global__ void pos_kernel(const float* __restrict__ wkp1,
                           const float* __restrict__ kp1d,
                           const float* __restrict__ desc2,
                           float* __restrict__ out) {
    const int i = blockIdx.x;
    const int c = threadIdx.x;            // 128 threads = 2 waves
    float y = wkp1[2 * i], x = wkp1[2 * i + 1];
    float py = fminf(fmaxf(y / (float)(HIMG - 1) * (float)(HC - 1), 0.0f), (float)(HC - 1));
    float px = fminf(fmaxf(x / (float)(WIMG - 1) * (float)(WC - 1), 0.0f), (float)(WC - 1));
    int y0 = min(max((int)floorf(py), 0), HC - 2);
    int x0 = min(max((int)floorf(px), 0), WC - 2);
    float wy = py - (float)y0;
    float wx = px - (float)x0;
    const float* d = desc2 + (size_t)c * (HC * WC) + y0 * WC + x0;
    float v00 = d[0], v01 = d[1], v10 = d[WC], v11 = d[WC + 1];
    float v = v00 * (1.0f - wy) * (1.0f - wx) + v01 * (1.0f - wy) * wx
            + v10 * wy * (1.0f - wx) + v11 * wy * wx;
    float a = kp1d[(size_t)i * CDIM + c];
    float s2 = v * v, sav = a * v;
    #pragma unroll
    for (int off = 32; off >= 1; off >>= 1) {
        s2  += __shfl_down(s2, off);
        sav += __shfl_down(sav, off);
    }
    __shared__ float p2[2], pav[2];
    int wave = threadIdx.x >> 6, lane = threadIdx.x & 63;
    if (lane == 0) { p2[wave] = s2; pav[wave] = sav; }
    __syncthreads();
    if (threadIdx.x == 0) {
        float nrm = sqrtf(p2[0] + p2[1]);
        float pd = (pav[0] + pav[1]) / fmaxf(nrm, 1e-12f);
        float l = fmaxf(1.0f - pd, 0.0f) * (256.0f / 3.0f);
        atomicAdd(out, l * INV_DENOM);
    }
}

// ---------- masked GEMM -> bf16 dots ----------
__global__ __launch_bounds__(256, 2)
void gemm_kernel(const ushort* __restrict__ A, const ushort* __restrict__ B,
                 const float* __restrict__ wkp1, const float* __restrict__ kp2,
                 ushort* __restrict__ dots, int m_off) {
    const int n0 = blockIdx.x * 128;
    const int m0 = m_off + blockIdx.y * 128;
    const int lane = threadIdx.x & 63;
    const int wave = threadIdx.x >> 6;
    const int wm = wave >> 1, wn = wave & 1;
    const int lrow = lane & 15, quad = lane >> 4;

    f32x4 acc[4][4];
    #pragma unroll
    for (int i = 0; i < 4; i++)
        #pragma unroll
        for (int j = 0; j < 4; j++) acc[i][j] = (f32x4){0.f, 0.f, 0.f, 0.f};

    const int mbase = m0 + wm * 64 + lrow;
    const int nbase = n0 + wn * 64 + lrow;
    #pragma unroll
    for (int kit = 0; kit < 4; kit++) {
        const int kk = kit * 32 + quad * 8;
        bf16x8 af[4], bfr[4];
        #pragma unroll
        for (int t = 0; t < 4; t++) {
            af[t]  = *(const bf16x8*)(A + (size_t)(mbase + t * 16) * CDIM + kk);
            bfr[t] = *(const bf16x8*)(B + (size_t)(nbase + t * 16) * CDIM + kk);
        }
        #pragma unroll
        for (int mt = 0; mt < 4; mt++)
            #pragma unroll
            for (int nt = 0; nt < 4; nt++)
                acc[mt][nt] = __builtin_amdgcn_mfma_f32_16x16x32_bf16(
                    af[mt], bfr[nt], acc[mt][nt], 0, 0, 0);
    }

    const float thr = 2.0f * sqrtf(32.0f) + 0.1f;
    const float thr2 = thr * thr;
    #pragma unroll
    for (int nt = 0; nt < 4; nt++) {
        int j = n0 + wn * 64 + nt * 16 + lrow;       // C/D: col = lane&15
        float ky = kp2[2 * j], kx = kp2[2 * j + 1];
        #pragma unroll
        for (int mt = 0; mt < 4; mt++) {
            #pragma unroll
            for (int r = 0; r < 4; r++) {
                int i = m0 + wm * 64 + mt * 16 + quad * 4 + r;  // row = (lane>>4)*4 + reg
                float wy = wkp1[2 * i], wx = wkp1[2 * i + 1];
                float dy = wy - ky, dx = wx - kx;
                float v = acc[mt][nt][r];
                if (dy * dy + dx * dx <= thr2) v -= 5.0f;
                dots[(size_t)(i - m_off) * N2 + j] = f2bf(v);
            }
        }
    }
}

// ---------- per-row top-256 hinge sum (candidate compaction + short bisect) ----------
// One WAVE per row: zero __syncthreads, zero LDS atomics, no register-residency
// assumptions. Single full-row pass compacts key-pairs with either half > T0=8.0
// into LDS (ballot+mbcnt); stats guarantee ~1950 candidates >= 256 (checked).
// Bisect ONLY the ~1600-u32 list over [key(8), key(32)] = 8 iterations.
// Exact: junk halves (<= T0) can never exceed any probed mid (mid >= key(T0));
// guards fall back to full restage + [-1,65535] bisect (same closed form).
// Rationale: R7 post-mortem showed any 16-iter full-row scan costs ~54us/chunk
// in VALU issue alone -- the pass count had to drop, not the implementation.
__global__ __launch_bounds__(128, 2)
void select_kernel(const ushort* __restrict__ dots, float* __restrict__ out) {
    const int wave = threadIdx.x >> 6;
    const int lane = threadIdx.x & 63;
    const int row = blockIdx.x * 2 + wave;

    __shared__ unsigned listU32[2][4096];     // 16 KB per wave
    unsigned* lst = listU32[wave];

    const uint4* rp4 = (const uint4*)(dots + (size_t)row * N2);  // 1024 uint4

    const unsigned T0  = 0xC100u;   // monotone key of bf16(8.0)
    const unsigned THI = 0xC200u;   // monotone key of bf16(32.0)

    // ---- pass 1: convert + count + compact candidates (u32 pair granularity)
    int base = 0;      // u32 slots written (wave-uniform)
    int cHi = 0;       // per-lane count of halves > THI
    #pragma unroll
    for (int j = 0; j < 16; j++) {
        uint4 w = rp4[lane + 64 * j];
        unsigned xs[4] = {w.x, w.y, w.z, w.w};
        #pragma unroll
        for (int u = 0; u < 4; u++) {
            unsigned kk = pair2key(xs[u]);
            unsigned lowk = kk & 0xFFFFu;
            bool cl = lowk > T0;
            bool ch = kk > ((T0 << 16) | 0xFFFFu);       // high half > T0
            cHi += (int)(lowk > THI) + (int)(kk > ((THI << 16) | 0xFFFFu));
            unsigned long long m = __ballot(cl || ch);
            int pre = __builtin_amdgcn_mbcnt_hi((unsigned)(m >> 32),
                      __builtin_amdgcn_mbcnt_lo((unsigned)m, 0u));
            if (cl || ch) lst[base + pre] = kk;
            base += (int)__popcll(m);
        }
    }
    #pragma unroll
    for (int off = 32; off >= 1; off >>= 1) cHi += __shfl_down(cHi, off);
    cHi = __shfl(cHi, 0);

    int L32 = base;
    int lo, hi;
    if (L32 >= 256 && cHi <= 255) {
        lo = (int)T0; hi = (int)THI;   // bracket invariants verified above
    } else {
        // degenerate row: restage everything raw (order irrelevant), full bisect
        #pragma unroll
        for (int j = 0; j < 16; j++) {
            uint4 w = rp4[lane + 64 * j];
            uint4 kq;
            kq.x = pair2key(w.x); kq.y = pair2key(w.y);
            kq.z = pair2key(w.z); kq.w = pair2key(w.w);
            ((uint4*)lst)[lane + 64 * j] = kq;
        }
        L32 = 4096; lo = -1; hi = 65535;
    }

    const int nU4   = (L32 + 3) >> 2;
    const int maxit = (nU4 + 63) >> 6;        // uint4 reads per lane
    // zero-pad u32s [L32, maxit*256) (key 0 can never beat any probed mid >= 0)
    for (int p = L32 + lane; p < maxit * 256; p += 64) lst[p] = 0u;

    // ---- bisect the list; invariant: cnt(>lo) >= 256, cnt(>hi) <= 255
    while (hi - lo > 1) {
        unsigned midu = (unsigned)((lo + hi) >> 1);
        unsigned midhi = (midu << 16) | 0xFFFFu;
        int c = 0;
        for (int j = 0; j < maxit; j++) {
            uint4 q = ((const uint4*)lst)[lane + 64 * j];
            c += (int)((q.x & 0xFFFFu) > midu) + (int)(q.x > midhi);
            c += (int)((q.y & 0xFFFFu) > midu) + (int)(q.y > midhi);
            c += (int)((q.z & 0xFFFFu) > midu) + (int)(q.z > midhi);
            c += (int)((q.w & 0xFFFFu) > midu) + (int)(q.w > midhi);
        }
        #pragma unroll
        for (int off = 32; off >= 1; off >>= 1) c += __shfl_down(c, off);
        c = __shfl(c, 0);
        if (c >= 256) lo = (int)midu; else hi = (int)midu;
    }
    const unsigned kt = (unsigned)hi;         // key of 256th-largest (attained)

    // ---- epilogue: exact closed form under ties
    float s = 0.f; int cgt = 0;
    const unsigned kthi = (kt << 16) | 0xFFFFu;
    for (int j = 0; j < maxit; j++) {
        uint4 q = ((const uint4*)lst)[lane + 64 * j];
        unsigned qs[4] = {q.x, q.y, q.z, q.w};
        #pragma unroll
        for (int u = 0; u < 4; u++) {
            unsigned lowk = qs[u] & 0xFFFFu, highk = qs[u] >> 16;
            if (lowk > kt)       { s += fmaxf(bf2f(key2bits(lowk)) - 0.2f, 0.0f); cgt++; }
            if (qs[u] > kthi)    { s += fmaxf(bf2f(key2bits(highk)) - 0.2f, 0.0f); cgt++; }
        }
    }
    #pragma unroll
    for (int off = 32; off >= 1; off >>= 1) {
        s += __shfl_down(s, off);
        cgt += __shfl_down(cgt, off);
    }
    if (lane == 0) {
        float vt = bf2f(key2bits(kt));
        float S = s + (float)(256 - cgt) * fmaxf(vt - 0.2f, 0.0f);
        atomicAdd(out, S * INV_DENOM);
    }
}

extern "C" void kernel_launch(void* const* d_in, const int* in_sizes, int n_in,
                              void* d_out, int out_size, void* d_ws, size_t ws_size,
                              hipStream_t stream) {
    const float* wkp1  = (const float*)d_in[1];
    const float* kp2   = (const float*)d_in[2];
    const float* kp1d  = (const float*)d_in[3];
    const float* kp2d  = (const float*)d_in[4];
    const float* desc2 = (const float*)d_in[5];
    float* out = (float*)d_out;

    ushort* Abf = (ushort*)d_ws;                 // 2 MB
    ushort* Bbf = Abf + (size_t)N1 * CDIM;       // 2 MB
    ushort* dots = Bbf + (size_t)N2 * CDIM;      // remainder: desc_dot chunks (bf16)

    size_t desc_bytes = (size_t)(N1 + N2) * CDIM * sizeof(ushort);
    size_t avail = (ws_size > desc_bytes) ? (ws_size - desc_bytes) : 0;
    long rows_chunk = (long)(avail / ((size_t)N2 * sizeof(ushort)));
    rows_chunk = (rows_chunk / 128) * 128;
    if (rows_chunk > N1) rows_chunk = N1;
    if (rows_chunk < 128) rows_chunk = 128;      // requires ws >= ~6 MB

    hipMemsetAsync(d_out, 0, sizeof(float), stream);

    int n4 = N1 * CDIM / 4;
    cvt_kernel<<<(n4 + 255) / 256, 256, 0, stream>>>(kp1d, Abf, n4);
    cvt_kernel<<<(n4 + 255) / 256, 256, 0, stream>>>(kp2d, Bbf, n4);

    pos_kernel<<<N1, 128, 0, stream>>>(wkp1, kp1d, desc2, out);

    for (int r0 = 0; r0 < N1; r0 += (int)rows_chunk) {
        int rows = (int)((N1 - r0 < rows_chunk) ? (N1 - r0) : rows_chunk);
        dim3 grid(N2 / 128, rows / 128);
        gemm_kernel<<<grid, 256, 0, stream>>>(Abf, Bbf, wkp1, kp2, dots, r0);
        select_kernel<<<rows / 2, 128, 0, stream>>>(dots, out);
    }
}